// Round 15
// baseline (466.984 us; speedup 1.0000x reference)
//
#include <hip/hip_runtime.h>
#include <hip/hip_bf16.h>
#include <math.h>

// HebbianBlock: B=4, T=4096, D=1024, H=8, d=128, C=64, N=64
// Round 15: k_scan_fused gains wave-TLP without work duplication: 512-thr
// blocks (8 waves) run BOTH 16-col qgroups of one bh (waves 0-3 / 4-7),
// grid 128. Waves/SIMD 1->2 so serial MFMA/LDS/barrier latency of one
// stream hides under the other. ST/vnL doubled per sub-group.
// k_wcvt / k_prep / k_gemm / k_chunk verbatim from passing Round 14.

#define T_LEN 4096
typedef unsigned short ushort;
typedef __attribute__((ext_vector_type(2))) unsigned short us2;
typedef __attribute__((ext_vector_type(4))) unsigned short us4;
typedef __attribute__((ext_vector_type(8))) unsigned short us8;
typedef __attribute__((ext_vector_type(8))) short short8v;
typedef __attribute__((ext_vector_type(4))) float f32x4;

__device__ __forceinline__ float bf2f(ushort u) {
  union { unsigned int u; float f; } c; c.u = ((unsigned int)u) << 16; return c.f;
}
__device__ __forceinline__ ushort f2bf(float x) {
  union { float f; unsigned int u; } c; c.f = x;
  unsigned int u = c.u + 0x7FFFu + ((c.u >> 16) & 1u);
  return (ushort)(u >> 16);
}
__device__ __forceinline__ void gload_lds16(const ushort* g, ushort* l) {
  __builtin_amdgcn_global_load_lds(
      (const __attribute__((address_space(1))) void*)g,
      (__attribute__((address_space(3))) void*)l, 16, 0, 0);
}

// ---------------- K0: W f32 -> bf16 ----------------
__global__ __launch_bounds__(256) void k_wcvt(
    const float* __restrict__ Ww, const float* __restrict__ Wr,
    ushort* __restrict__ Wwb, ushort* __restrict__ Wrb)
{
  size_t i = ((size_t)blockIdx.x * 256 + threadIdx.x) * 8;
  float4 p0 = *(const float4*)(Ww + i), p1 = *(const float4*)(Ww + i + 4);
  us8 o;
  o[0]=f2bf(p0.x); o[1]=f2bf(p0.y); o[2]=f2bf(p0.z); o[3]=f2bf(p0.w);
  o[4]=f2bf(p1.x); o[5]=f2bf(p1.y); o[6]=f2bf(p1.z); o[7]=f2bf(p1.w);
  *(us8*)(Wwb + i) = o;
  float4 q0 = *(const float4*)(Wr + i), q1 = *(const float4*)(Wr + i + 4);
  us8 o2;
  o2[0]=f2bf(q0.x); o2[1]=f2bf(q0.y); o2[2]=f2bf(q0.z); o2[3]=f2bf(q0.w);
  o2[4]=f2bf(q1.x); o2[5]=f2bf(q1.y); o2[6]=f2bf(q1.z); o2[7]=f2bf(q1.w);
  *(us8*)(Wrb + i) = o2;
}

// ---------------- K1: rk + beta + xb ----------------
__global__ __launch_bounds__(128) void k_prep(
    const float* __restrict__ x, const float* __restrict__ Wb,
    ushort* __restrict__ rk, float* __restrict__ beta, ushort* __restrict__ xb)
{
  int bt = blockIdx.x;
  int b = bt >> 12, t = bt & 4095;
  int tid = threadIdx.x;
  __shared__ float xs[1024];
  __shared__ float red[16];
  {
    const float4* x4 = (const float4*)(x + (size_t)bt * 1024);
    float4* xs4 = (float4*)xs;
    xs4[tid] = x4[tid];
    xs4[tid + 128] = x4[tid + 128];
  }
  __syncthreads();
  int h = tid >> 4;
  int e0 = h * 128 + (tid & 15) * 8;
  float ss = 0.f;
  #pragma unroll
  for (int s = 0; s < 8; ++s) { float v = xs[e0 + s]; ss += v * v; }
  #pragma unroll
  for (int m = 1; m < 16; m <<= 1) ss += __shfl_xor(ss, m, 64);
  float inv = 1.f / fmaxf(sqrtf(ss), 1e-12f);
  {
    int bh = b * 8 + h;
    us8 o;
    #pragma unroll
    for (int s = 0; s < 8; ++s) o[s] = f2bf(xs[e0 + s] * inv);
    *(us8*)(rk + ((size_t)bh * T_LEN + t) * 128 + (tid & 15) * 8) = o;
  }
  {
    us8 o;
    #pragma unroll
    for (int s = 0; s < 8; ++s) o[s] = f2bf(xs[tid * 8 + s]);
    *(us8*)(xb + (size_t)bt * 1024 + tid * 8) = o;
  }
  const float* xk = xs + tid * 8;
  #pragma unroll
  for (int h2 = 0; h2 < 8; ++h2) {
    const float* wb = Wb + (size_t)h2 * 1024 + tid * 8;
    float p = 0.f;
    #pragma unroll
    for (int s = 0; s < 8; ++s) p += xk[s] * wb[s];
    #pragma unroll
    for (int m = 1; m < 64; m <<= 1) p += __shfl_xor(p, m, 64);
    if ((tid & 63) == 0) red[(tid >> 6) * 8 + h2] = p;
  }
  __syncthreads();
  if (tid < 8) {
    float s = red[tid] + red[8 + tid];
    beta[((size_t)(b * 8 + tid)) * T_LEN + t] = 1.f / (1.f + expf(-s));
  }
}

// ---------------- K2/K5: bf16 MFMA GEMM, global_load_lds staging ----------------
template<int MODE>
__global__ __launch_bounds__(256) void k_gemm(
    const ushort* __restrict__ A, const ushort* __restrict__ Wb,
    const float* __restrict__ beta, const float* __restrict__ xadd,
    void* __restrict__ out_)
{
  __shared__ ushort As[128 * 32];
  __shared__ ushort Bs[128 * 32];
  const int n0 = blockIdx.x * 128;
  const int m0 = blockIdx.y * 128;
  const int tid = threadIdx.x;
  const int lane = tid & 63;
  const int wid = tid >> 6;
  const int wr = wid >> 1, wc = wid & 1;
  const int c = lane & 15, g = lane >> 4;
  const int lrow = lane >> 2;
  const int lseg = lane & 3;

  f32x4 acc[4][4] = {};

  for (int k0 = 0; k0 < 1024; k0 += 32) {
    #pragma unroll
    for (int u = 0; u < 2; ++u) {
      const int rbase = wid * 32 + u * 16;
      const int row = rbase + lrow;
      gload_lds16(A  + (size_t)(m0 + row) * 1024 + k0 + lseg * 8, &As[rbase * 32]);
      gload_lds16(Wb + (size_t)(n0 + row) * 1024 + k0 + lseg * 8, &Bs[rbase * 32]);
    }
    __syncthreads();
    short8v af[4], bf[4];
    #pragma unroll
    for (int mi = 0; mi < 4; ++mi)
      af[mi] = *(const short8v*)&As[(wr * 64 + mi * 16 + c) * 32 + g * 8];
    #pragma unroll
    for (int ni = 0; ni < 4; ++ni)
      bf[ni] = *(const short8v*)&Bs[(wc * 64 + ni * 16 + c) * 32 + g * 8];
    #pragma unroll
    for (int mi = 0; mi < 4; ++mi)
      #pragma unroll
      for (int ni = 0; ni < 4; ++ni)
        acc[mi][ni] = __builtin_amdgcn_mfma_f32_16x16x32_bf16(af[mi], bf[ni], acc[mi][ni], 0, 0, 0);
    __syncthreads();
  }

  if (MODE == 0) {
    ushort* vb = (ushort*)out_;
    const int hh = n0 >> 7;
    #pragma unroll
    for (int mi = 0; mi < 4; ++mi) {
      #pragma unroll
      for (int ni = 0; ni < 4; ++ni) {
        int jc = wc * 64 + ni * 16 + c;
        #pragma unroll
        for (int j = 0; j < 4; ++j) {
          int m = m0 + wr * 64 + mi * 16 + g * 4 + j;
          int b = m >> 12, t = m & 4095;
          size_t base = (size_t)(b * 8 + hh) * T_LEN + t;
          float bv = beta[base];
          vb[base * 128 + jc] = f2bf(acc[mi][ni][j] * bv);
        }
      }
    }
  } else {
    float* out = (float*)out_;
    #pragma unroll
    for (int mi = 0; mi < 4; ++mi) {
      #pragma unroll
      for (int ni = 0; ni < 4; ++ni) {
        int n = n0 + wc * 64 + ni * 16 + c;
        #pragma unroll
        for (int j = 0; j < 4; ++j) {
          int m = m0 + wr * 64 + mi * 16 + g * 4 + j;
          size_t idx = (size_t)m * 1024 + n;
          out[idx] = xadd[idx] + acc[mi][ni][j];
        }
      }
    }
  }
}

// ---------------- K3: chunk kernel (verbatim R12/R10) ----------------
__global__ __launch_bounds__(256) void k_chunk(
    const ushort* __restrict__ rk, ushort* __restrict__ vb,
    ushort* __restrict__ wkcum, ushort* __restrict__ attn,
    const float* __restrict__ beta, const float* __restrict__ decay,
    ushort* __restrict__ wkdwT)
{
  int bh = blockIdx.x >> 6;
  int n = blockIdx.x & 63;
  int h = bh & 7;
  int tid = threadIdx.x;
  int lane = tid & 63, w = tid >> 6;
  int c = lane & 15, g = lane >> 4;

  __shared__ __align__(16) char smem[39952];
  ushort* rkb  = (ushort*)smem;
  float*  redp = (float*)smem;
  ushort* Ab1  = (ushort*)smem;
  ushort* Ab2  = (ushort*)(smem + 9216);
  float*  Af   = (float*)(smem + 21760);
  ushort* xT   = (ushort*)(smem + 18432);
  float*  gpow  = (float*)(smem + 39168);
  float*  betaS = (float*)(smem + 39432);
  float*  bd    = (float*)(smem + 39688);

  float lg = logf(1.f / (1.f + expf(-decay[h])));
  if (tid < 65) gpow[tid] = expf(lg * (float)tid);
  if (tid < 64) betaS[tid] = beta[(size_t)bh * T_LEN + n * 64 + tid];
  const int t0 = n * 64;
  const size_t bhbase = (size_t)bh * T_LEN;
  const us8 zero8 = {0, 0, 0, 0, 0, 0, 0, 0};

  #pragma unroll
  for (int u = 0; u < 5; ++u) {
    int idx = tid + u * 256;
    int row = idx >> 4, cb = idx & 15;
    us8 v = zero8;
    int t = t0 + row - 1;
    if (row <= 64 && t >= 0) v = *(const us8*)(rk + (bhbase + t) * 128 + cb * 8);
    *(us8*)&rkb[row * 136 + cb * 8] = v;
  }
  for (int idx = tid; idx < 64 * 68; idx += 256) Af[idx] = 0.f;
  __syncthreads();
  if (tid < 64) bd[tid] = betaS[tid] * gpow[tid + 1];

  const size_t abase = ((size_t)bh * 64 + n) * 4096;
  {
    const int TR[14] = {0,1,1,2,2,2,3,3,3,3,4,4,4,4};
    const int TC[14] = {0,0,1,0,1,2,0,1,2,3,0,1,2,3};
    #pragma unroll
    for (int ti = 0; ti < 14; ++ti) {
      if ((ti & 3) != w) continue;
      const int tr = TR[ti], tc = TC[ti];
      f32x4 acc = {0.f, 0.f, 0.f, 0.f};
      #pragma unroll
      for (int ks = 0; ks < 4; ++ks) {
        short8v a = *(const short8v*)&rkb[(tr * 16 + c) * 136 + ks * 32 + g * 8];
        short8v b = *(const short8v*)&rkb[(tc * 16 + c) * 136 + ks * 32 + g * 8];
        acc = __builtin_amdgcn_mfma_f32_16x16x32_bf16(a, b, acc, 0, 0, 0);
      }
      #pragma unroll
      for (int r = 0; r < 4; ++r) {
        int a_ = tr * 16 + g * 4 + r;
        int j = tc * 16 + c;
        float val = acc[r];
        if (a_ <= 63) Af[a_ * 68 + j] = (a_ > j) ? (-betaS[a_] * val * gpow[a_ - j]) : 0.f;
        if (a_ >= 1 && a_ <= 64) {
          if (j <= a_ - 1)      attn[abase + (size_t)(a_ - 1) * 64 + j] = f2bf(val * gpow[a_ - 1 - j]);
          else if (a_ <= 63)    attn[abase + (size_t)(a_ - 1) * 64 + j] = 0;
        }
      }
    }
  }
  {
    const int ZR[6] = {0,0,0,1,1,2};
    const int ZC[6] = {1,2,3,2,3,3};
    int rr = tid >> 4, cc2 = tid & 15;
    #pragma unroll
    for (int z = 0; z < 6; ++z) {
      int r_att = ZR[z] * 16 - 1 + rr;
      if (r_att >= 0) attn[abase + (size_t)r_att * 64 + ZC[z] * 16 + cc2] = 0;
    }
  }
  __syncthreads();

  {
    int k = tid & 63, sp = tid >> 6;
    for (int i = 1; i < 64; ++i) {
      float part = 0.f;
      #pragma unroll
      for (int jj = 0; jj < 16; ++jj) {
        int j = sp * 16 + jj;
        part += Af[i * 68 + j] * Af[j * 68 + k];
      }
      redp[sp * 64 + k] = part;
      __syncthreads();
      if (tid < 64) Af[i * 68 + tid] += redp[tid] + redp[64 + tid] + redp[128 + tid] + redp[192 + tid];
      __syncthreads();
    }
  }
  {
    int i = tid >> 2, j0 = (tid & 3) * 16;
    #pragma unroll
    for (int jj = 0; jj < 16; ++jj) {
      int j = j0 + jj;
      float av = Af[i * 68 + j] + ((i == j) ? 1.f : 0.f);
      Ab1[i * 72 + j] = f2bf(av * bd[j]);
      Ab2[i * 72 + j] = f2bf(av);
    }
  }
  __syncthreads();

  #pragma unroll
  for (int u = 0; u < 4; ++u) {
    int idx = tid + u * 256;
    int j = idx & 63, eb = idx >> 6;
    int t = t0 + j - 1;
    us8 v = zero8;
    if (t >= 0) v = *(const us8*)(rk + (bhbase + t) * 128 + eb * 8);
    #pragma unroll
    for (int s = 0; s < 8; ++s) xT[(eb * 8 + s) * 72 + j] = v[s];
  }
  __syncthreads();

  {
    f32x4 acc[8] = {};
    #pragma unroll
    for (int ks = 0; ks < 2; ++ks) {
      short8v a = *(const short8v*)&Ab1[(w * 16 + c) * 72 + ks * 32 + g * 8];
      #pragma unroll
      for (int nt = 0; nt < 8; ++nt) {
        short8v b = *(const short8v*)&xT[(nt * 16 + c) * 72 + ks * 32 + g * 8];
        acc[nt] = __builtin_amdgcn_mfma_f32_16x16x32_bf16(a, b, acc[nt], 0, 0, 0);
      }
    }
    #pragma unroll
    for (int nt = 0; nt < 8; ++nt)
      #pragma unroll
      for (int r = 0; r < 4; ++r) {
        int i = w * 16 + g * 4 + r, e = nt * 16 + c;
        wkcum[(bhbase + t0 + i) * 128 + e] = f2bf(acc[nt][r]);
      }
  }
  {
    const size_t kbase = ((size_t)bh * 64 + n) * 8192;
    #pragma unroll
    for (int u = 0; u < 4; ++u) {
      int idx = tid + u * 256;
      int e = idx >> 3, seg = idx & 7;
      us8 v = *(const us8*)&xT[e * 72 + seg * 8];
      us8 o;
      #pragma unroll
      for (int s = 0; s < 8; ++s) o[s] = f2bf(bf2f(v[s]) * gpow[63 - (seg * 8 + s)]);
      *(us8*)(wkdwT + kbase + (size_t)e * 64 + seg * 8) = o;
    }
  }
  __syncthreads();
  #pragma unroll
  for (int u = 0; u < 4; ++u) {
    int idx = tid + u * 256;
    int j = idx & 63, eb = idx >> 6;
    us8 v = *(const us8*)(vb + (bhbase + t0 + j) * 128 + eb * 8);
    #pragma unroll
    for (int s = 0; s < 8; ++s) xT[(eb * 8 + s) * 72 + j] = v[s];
  }
  __syncthreads();
  {
    f32x4 acc[8] = {};
    #pragma unroll
    for (int ks = 0; ks < 2; ++ks) {
      short8v a = *(const short8v*)&Ab2[(w * 16 + c) * 72 + ks * 32 + g * 8];
      #pragma unroll
      for (int nt = 0; nt < 8; ++nt) {
        short8v b = *(const short8v*)&xT[(nt * 16 + c) * 72 + ks * 32 + g * 8];
        acc[nt] = __builtin_amdgcn_mfma_f32_16x16x32_bf16(a, b, acc[nt], 0, 0, 0);
      }
    }
    #pragma unroll
    for (int nt = 0; nt < 8; ++nt)
      #pragma unroll
      for (int r = 0; r < 4; ++r) {
        int i = w * 16 + g * 4 + r, e = nt * 16 + c;
        vb[(bhbase + t0 + i) * 128 + e] = f2bf(acc[nt][r]);
      }
  }
}

// ---------------- K4: fused MFMA scan, 8 waves = 2 qgroups of one bh ----------------
// grid 128 = 32 bh x 4 qpairs. waves 0-3 -> qgroup (qpair*2), waves 4-7 ->
// qgroup (qpair*2+1). Per-sub ST/vnL. Numerics identical to R12/R14.
#define SCAN_STEP(W_, R_, T_, K_, V_, nW, nR, nT, nK, nV, n_) {                 \
  const int t0s = (n_) * 64;                                                    \
  { const int np = ((n_) < 63) ? (n_) + 1 : 63;                                 \
    const size_t rb = (bhbase + (size_t)(np * 64 + 16 * w + c)) * 128;          \
    _Pragma("unroll")                                                           \
    for (int ks = 0; ks < 4; ++ks) {                                            \
      nW[ks] = *(const short8v*)(wkcum + rb + ks * 32 + g * 8);                 \
      nR[ks] = *(const short8v*)(rk    + rb + ks * 32 + g * 8); }               \
    const size_t ab = ((size_t)bh * 64 + np) * 4096 + (size_t)(16 * w + c) * 64;\
    nT[0] = *(const short8v*)(attn + ab + g * 8);                               \
    nT[1] = *(const short8v*)(attn + ab + 32 + g * 8);                          \
    const size_t kb = ((size_t)bh * 64 + np) * 8192;                            \
    nK[0] = *(const short8v*)(wkdwT + kb + (size_t)(32 * w + c) * 64 + g * 8);  \
    nK[1] = *(const short8v*)(wkdwT + kb + (size_t)(32 * w + c) * 64 + 32 + g * 8); \
    nK[2] = *(const short8v*)(wkdwT + kb + (size_t)(32 * w + 16 + c) * 64 + g * 8); \
    nK[3] = *(const short8v*)(wkdwT + kb + (size_t)(32 * w + 16 + c) * 64 + 32 + g * 8); \
    _Pragma("unroll")                                                           \
    for (int r = 0; r < 4; ++r)                                                 \
      nV[r] = vb[(bhbase + (size_t)(np * 64 + 16 * w + 4 * g + r)) * 128 + q0 + c]; } \
  f32x4 accA = {}, accB = {};                                                   \
  _Pragma("unroll")                                                             \
  for (int ks = 0; ks < 4; ++ks) {                                              \
    short8v b0 = *(const short8v*)&STp[c * 136 + ks * 32 + g * 8];              \
    accA = __builtin_amdgcn_mfma_f32_16x16x32_bf16(W_[ks], b0, accA, 0, 0, 0);  \
    accB = __builtin_amdgcn_mfma_f32_16x16x32_bf16(R_[ks], b0, accB, 0, 0, 0); }\
  _Pragma("unroll")                                                             \
  for (int r = 0; r < 4; ++r) {                                                 \
    int i = 16 * w + 4 * g + r;                                                 \
    accB[r] *= gB[r];                                                           \
    vnLp[c * 72 + i] = f2bf(bf2f(V_[r]) - accA[r]); }                           \
  asm volatile("s_waitcnt lgkmcnt(0)" ::: "memory");                            \
  __builtin_amdgcn_s_barrier();                                                 \
  short8v vf0 = *(const short8v*)&vnLp[c * 72 + g * 8];                         \
  short8v vf1 = *(const short8v*)&vnLp[c * 72 + 32 + g * 8];                    \
  accB = __builtin_amdgcn_mfma_f32_16x16x32_bf16(T_[0], vf0, accB, 0, 0, 0);    \
  accB = __builtin_amdgcn_mfma_f32_16x16x32_bf16(T_[1], vf1, accB, 0, 0, 0);    \
  _Pragma("unroll")                                                             \
  for (int r = 0; r < 4; ++r) {                                                 \
    int i = 16 * w + 4 * g + r;                                                 \
    og[((size_t)b_ * T_LEN + t0s + i) * 1024 + h * 128 + q0 + c] = f2bf(accB[r]); } \
  _Pragma("unroll")                                                             \
  for (int r = 0; r < 4; ++r) { accS0[r] *= ct; accS1[r] *= ct; }               \
  accS0 = __builtin_amdgcn_mfma_f32_16x16x32_bf16(K_[0], vf0, accS0, 0, 0, 0);  \
  accS0 = __builtin_amdgcn_mfma_f32_16x16x32_bf16(K_[1], vf1, accS0, 0, 0, 0);  \
  accS1 = __builtin_amdgcn_mfma_f32_16x16x32_bf16(K_[2], vf0, accS1, 0, 0, 0);  \
  accS1 = __builtin_amdgcn_mfma_f32_16x16x32_bf16(K_[3], vf1, accS1, 0, 0, 0);  \
  _Pragma("unroll")                                                             \
  for (int r = 0; r < 4; ++r) {                                                 \
    int p0r = 32 * w + 4 * g + r;                                               \
    STp[c * 136 + p0r]      = f2bf(accS0[r]);                                   \
    STp[c * 136 + p0r + 16] = f2bf(accS1[r]); }                                 \
  asm volatile("s_waitcnt lgkmcnt(0)" ::: "memory");                            \
  __builtin_amdgcn_s_barrier();                                                 \
}

__global__ __launch_bounds__(512) void k_scan_fused(
    const ushort* __restrict__ rk, const ushort* __restrict__ vb,
    const ushort* __restrict__ wkcum, const ushort* __restrict__ attn,
    const ushort* __restrict__ wkdwT, const float* __restrict__ decay,
    ushort* __restrict__ og)
{
  const int bh = blockIdx.x & 31;          // same-bh pair; pairs share L1/L2
  const int qpair = blockIdx.x >> 5;       // 0..3
  const int b_ = bh >> 3, h = bh & 7;
  const int tid = threadIdx.x;
  const int lane = tid & 63, w8 = tid >> 6;  // 0..7
  const int sub = w8 >> 2;                   // qgroup within pair
  const int w = w8 & 3;                      // row band
  const int q0 = (qpair * 2 + sub) * 16;
  const int c = lane & 15, g = lane >> 4;

  __shared__ ushort ST[2][16 * 136];
  __shared__ ushort vnL[2][16 * 72];
  __shared__ float gpow[65];
  ushort* STp  = &ST[sub][0];
  ushort* vnLp = &vnL[sub][0];

  float lg = logf(1.f / (1.f + expf(-decay[h])));
  if (tid < 65) gpow[tid] = expf(lg * (float)tid);
  for (int idx = tid; idx < 2 * 16 * 136; idx += 512) ((ushort*)ST)[idx] = 0;
  __syncthreads();
  const float ct = gpow[64];
  float gB[4];
  #pragma unroll
  for (int r = 0; r < 4; ++r) gB[r] = gpow[16 * w + 4 * g + r + 1];
  const size_t bhbase = (size_t)bh * T_LEN;

  f32x4 accS0 = {}, accS1 = {};
  short8v aW[4], aR[4], aT[2], aK[4];
  short8v bW[4], bR[4], bT[2], bK[4];
  ushort aV[4], bV[4];
  {
    const size_t rb = (bhbase + (size_t)(16 * w + c)) * 128;
    #pragma unroll
    for (int ks = 0; ks < 4; ++ks) {
      aW[ks] = *(const short8v*)(wkcum + rb + ks * 32 + g * 8);
      aR[ks] = *(const short8v*)(rk + rb + ks * 32 + g * 8);
    }
    const size_t ab = (size_t)bh * 64 * 4096 + (size_t)(16 * w + c) * 64;
    aT[0] = *(const short8v*)(attn + ab + g * 8);
    aT[1] = *(const short8v*)(attn + ab + 32 + g * 8);
    const size_t kb = (size_t)bh * 64 * 8192;
    aK[0] = *(const short8v*)(wkdwT + kb + (size_t)(32 * w + c) * 64 + g * 8);
    aK[1] = *(const short8v*)(wkdwT + kb + (size_t)(32 * w + c) * 64 + 32 + g * 8);
    aK[2] = *(const short8v*)(wkdwT + kb + (size_t)(32 * w + 16 + c) * 64 + g * 8);
    aK[3] = *(const short8v*)(wkdwT + kb + (size_t)(32 * w + 16 + c) * 64 + 32 + g * 8);
    #pragma unroll
    for (int r = 0; r < 4; ++r)
      aV[r] = vb[(bhbase + (size_t)(16 * w + 4 * g + r)) * 128 + q0 + c];
  }
  for (int n = 0; n < 64; n += 2) {
    SCAN_STEP(aW, aR, aT, aK, aV, bW, bR, bT, bK, bV, n);
    SCAN_STEP(bW, bR, bT, bK, bV, aW, aR, aT, aK, aV, n + 1);
  }
}

extern "C" void kernel_launch(void* const* d_in, const int* in_sizes, int n_in,
                              void* d_out, int out_size, void* d_ws, size_t ws_size,
                              hipStream_t stream) {
  const float* x   = (const float*)d_in[0];
  const float* Ww  = (const float*)d_in[1];
  const float* Wr  = (const float*)d_in[2];
  const float* Wb  = (const float*)d_in[3];
  const float* dec = (const float*)d_in[4];
  float* out = (float*)d_out;
  ushort* ws = (ushort*)d_ws;
  const size_t SZ = 16777216ull;
  ushort* rk    = ws;
  ushort* vb    = ws + SZ;
  ushort* wkcum = ws + 2 * SZ;
  ushort* og    = ws + 3 * SZ;
  ushort* attn  = ws + 4 * SZ;
  float*  beta  = (float*)(ws + 4 * SZ + 8388608ull);
  ushort* wkdwT = ws + 4 * SZ + 8388608ull + 262144ull;
  ushort* Wwb   = ws + 92536832ull;
  ushort* Wrb   = ws + 93585408ull;
  ushort* xb    = og;
  const size_t NEED = 189267968ull;
  if (ws_size < NEED) {
    hipMemcpyAsync(d_out, (const void*)x, (size_t)out_size * 4, hipMemcpyDeviceToDevice, stream);
    return;
  }

  k_wcvt<<<dim3(512), dim3(256), 0, stream>>>(Ww, Wr, Wwb, Wrb);
  k_prep<<<dim3(16384), dim3(128), 0, stream>>>(x, Wb, rk, beta, xb);
  k_gemm<0><<<dim3(8, 128), dim3(256), 0, stream>>>(xb, Wwb, beta, nullptr, (void*)vb);
  k_chunk<<<dim3(2048), dim3(256), 0, stream>>>(rk, vb, wkcum, attn, beta, dec, wkdwT);
  k_scan_fused<<<dim3(128), dim3(512), 0, stream>>>(rk, vb, wkcum, attn, wkdwT, dec, og);
  k_gemm<1><<<dim3(8, 128), dim3(256), 0, stream>>>(og, Wrb, nullptr, (const float*)x, (void*)out);
}

// Round 16
// 391.653 us; speedup vs baseline: 1.1923x; 1.1923x over previous
//
#include <hip/hip_runtime.h>
#include <hip/hip_bf16.h>
#include <math.h>

// HebbianBlock: B=4, T=4096, D=1024, H=8, d=128, C=64, N=64
// Round 16: revert scan to R14 (R15's 8-wave pairing coupled streams at the
// block-wide barrier: 121->217us). NEW: k_gemm 2-phase double-buffered
// global_load_lds staging (T3-minimum recipe) — 1 barrier/tile, next-tile
// loads hide under MFMA. Everything else verbatim R14.

#define T_LEN 4096
typedef unsigned short ushort;
typedef __attribute__((ext_vector_type(2))) unsigned short us2;
typedef __attribute__((ext_vector_type(4))) unsigned short us4;
typedef __attribute__((ext_vector_type(8))) unsigned short us8;
typedef __attribute__((ext_vector_type(8))) short short8v;
typedef __attribute__((ext_vector_type(4))) float f32x4;

__device__ __forceinline__ float bf2f(ushort u) {
  union { unsigned int u; float f; } c; c.u = ((unsigned int)u) << 16; return c.f;
}
__device__ __forceinline__ ushort f2bf(float x) {
  union { float f; unsigned int u; } c; c.f = x;
  unsigned int u = c.u + 0x7FFFu + ((c.u >> 16) & 1u);
  return (ushort)(u >> 16);
}
__device__ __forceinline__ void gload_lds16(const ushort* g, ushort* l) {
  __builtin_amdgcn_global_load_lds(
      (const __attribute__((address_space(1))) void*)g,
      (__attribute__((address_space(3))) void*)l, 16, 0, 0);
}

// ---------------- K0: W f32 -> bf16 ----------------
__global__ __launch_bounds__(256) void k_wcvt(
    const float* __restrict__ Ww, const float* __restrict__ Wr,
    ushort* __restrict__ Wwb, ushort* __restrict__ Wrb)
{
  size_t i = ((size_t)blockIdx.x * 256 + threadIdx.x) * 8;
  float4 p0 = *(const float4*)(Ww + i), p1 = *(const float4*)(Ww + i + 4);
  us8 o;
  o[0]=f2bf(p0.x); o[1]=f2bf(p0.y); o[2]=f2bf(p0.z); o[3]=f2bf(p0.w);
  o[4]=f2bf(p1.x); o[5]=f2bf(p1.y); o[6]=f2bf(p1.z); o[7]=f2bf(p1.w);
  *(us8*)(Wwb + i) = o;
  float4 q0 = *(const float4*)(Wr + i), q1 = *(const float4*)(Wr + i + 4);
  us8 o2;
  o2[0]=f2bf(q0.x); o2[1]=f2bf(q0.y); o2[2]=f2bf(q0.z); o2[3]=f2bf(q0.w);
  o2[4]=f2bf(q1.x); o2[5]=f2bf(q1.y); o2[6]=f2bf(q1.z); o2[7]=f2bf(q1.w);
  *(us8*)(Wrb + i) = o2;
}

// ---------------- K1: rk + beta + xb ----------------
__global__ __launch_bounds__(128) void k_prep(
    const float* __restrict__ x, const float* __restrict__ Wb,
    ushort* __restrict__ rk, float* __restrict__ beta, ushort* __restrict__ xb)
{
  int bt = blockIdx.x;
  int b = bt >> 12, t = bt & 4095;
  int tid = threadIdx.x;
  __shared__ float xs[1024];
  __shared__ float red[16];
  {
    const float4* x4 = (const float4*)(x + (size_t)bt * 1024);
    float4* xs4 = (float4*)xs;
    xs4[tid] = x4[tid];
    xs4[tid + 128] = x4[tid + 128];
  }
  __syncthreads();
  int h = tid >> 4;
  int e0 = h * 128 + (tid & 15) * 8;
  float ss = 0.f;
  #pragma unroll
  for (int s = 0; s < 8; ++s) { float v = xs[e0 + s]; ss += v * v; }
  #pragma unroll
  for (int m = 1; m < 16; m <<= 1) ss += __shfl_xor(ss, m, 64);
  float inv = 1.f / fmaxf(sqrtf(ss), 1e-12f);
  {
    int bh = b * 8 + h;
    us8 o;
    #pragma unroll
    for (int s = 0; s < 8; ++s) o[s] = f2bf(xs[e0 + s] * inv);
    *(us8*)(rk + ((size_t)bh * T_LEN + t) * 128 + (tid & 15) * 8) = o;
  }
  {
    us8 o;
    #pragma unroll
    for (int s = 0; s < 8; ++s) o[s] = f2bf(xs[tid * 8 + s]);
    *(us8*)(xb + (size_t)bt * 1024 + tid * 8) = o;
  }
  const float* xk = xs + tid * 8;
  #pragma unroll
  for (int h2 = 0; h2 < 8; ++h2) {
    const float* wb = Wb + (size_t)h2 * 1024 + tid * 8;
    float p = 0.f;
    #pragma unroll
    for (int s = 0; s < 8; ++s) p += xk[s] * wb[s];
    #pragma unroll
    for (int m = 1; m < 64; m <<= 1) p += __shfl_xor(p, m, 64);
    if ((tid & 63) == 0) red[(tid >> 6) * 8 + h2] = p;
  }
  __syncthreads();
  if (tid < 8) {
    float s = red[tid] + red[8 + tid];
    beta[((size_t)(b * 8 + tid)) * T_LEN + t] = 1.f / (1.f + expf(-s));
  }
}

// ---------------- K2/K5: bf16 MFMA GEMM, 2-phase dbuf global_load_lds ----------------
template<int MODE>
__global__ __launch_bounds__(256) void k_gemm(
    const ushort* __restrict__ A, const ushort* __restrict__ Wb,
    const float* __restrict__ beta, const float* __restrict__ xadd,
    void* __restrict__ out_)
{
  __shared__ ushort As[2][128 * 32];
  __shared__ ushort Bs[2][128 * 32];
  const int n0 = blockIdx.x * 128;
  const int m0 = blockIdx.y * 128;
  const int tid = threadIdx.x;
  const int lane = tid & 63;
  const int wid = tid >> 6;
  const int wr = wid >> 1, wc = wid & 1;
  const int c = lane & 15, g = lane >> 4;
  const int lrow = lane >> 2;
  const int lseg = lane & 3;

  f32x4 acc[4][4] = {};

#define GEMM_STAGE(buf, k0s) {                                                  \
    _Pragma("unroll")                                                           \
    for (int u = 0; u < 2; ++u) {                                               \
      const int rbase = wid * 32 + u * 16;                                      \
      const int row = rbase + lrow;                                             \
      gload_lds16(A  + (size_t)(m0 + row) * 1024 + (k0s) + lseg * 8, &As[buf][rbase * 32]); \
      gload_lds16(Wb + (size_t)(n0 + row) * 1024 + (k0s) + lseg * 8, &Bs[buf][rbase * 32]); \
    } }

  GEMM_STAGE(0, 0);
  __syncthreads();                 // buf0 ready
  int cur = 0;
  for (int t = 0; t < 32; ++t) {
    if (t < 31) GEMM_STAGE(cur ^ 1, (t + 1) * 32);   // next tile in flight
    short8v af[4], bf[4];
    #pragma unroll
    for (int mi = 0; mi < 4; ++mi)
      af[mi] = *(const short8v*)&As[cur][(wr * 64 + mi * 16 + c) * 32 + g * 8];
    #pragma unroll
    for (int ni = 0; ni < 4; ++ni)
      bf[ni] = *(const short8v*)&Bs[cur][(wc * 64 + ni * 16 + c) * 32 + g * 8];
    #pragma unroll
    for (int mi = 0; mi < 4; ++mi)
      #pragma unroll
      for (int ni = 0; ni < 4; ++ni)
        acc[mi][ni] = __builtin_amdgcn_mfma_f32_16x16x32_bf16(af[mi], bf[ni], acc[mi][ni], 0, 0, 0);
    __syncthreads();               // drains next-tile loads AFTER MFMA phase
    cur ^= 1;
  }
#undef GEMM_STAGE

  if (MODE == 0) {
    ushort* vb = (ushort*)out_;
    const int hh = n0 >> 7;
    #pragma unroll
    for (int mi = 0; mi < 4; ++mi) {
      #pragma unroll
      for (int ni = 0; ni < 4; ++ni) {
        int jc = wc * 64 + ni * 16 + c;
        #pragma unroll
        for (int j = 0; j < 4; ++j) {
          int m = m0 + wr * 64 + mi * 16 + g * 4 + j;
          int b = m >> 12, t = m & 4095;
          size_t base = (size_t)(b * 8 + hh) * T_LEN + t;
          float bv = beta[base];
          vb[base * 128 + jc] = f2bf(acc[mi][ni][j] * bv);
        }
      }
    }
  } else {
    float* out = (float*)out_;
    #pragma unroll
    for (int mi = 0; mi < 4; ++mi) {
      #pragma unroll
      for (int ni = 0; ni < 4; ++ni) {
        int n = n0 + wc * 64 + ni * 16 + c;
        #pragma unroll
        for (int j = 0; j < 4; ++j) {
          int m = m0 + wr * 64 + mi * 16 + g * 4 + j;
          size_t idx = (size_t)m * 1024 + n;
          out[idx] = xadd[idx] + acc[mi][ni][j];
        }
      }
    }
  }
}

// ---------------- K3: chunk kernel (verbatim R12/R10) ----------------
__global__ __launch_bounds__(256) void k_chunk(
    const ushort* __restrict__ rk, ushort* __restrict__ vb,
    ushort* __restrict__ wkcum, ushort* __restrict__ attn,
    const float* __restrict__ beta, const float* __restrict__ decay,
    ushort* __restrict__ wkdwT)
{
  int bh = blockIdx.x >> 6;
  int n = blockIdx.x & 63;
  int h = bh & 7;
  int tid = threadIdx.x;
  int lane = tid & 63, w = tid >> 6;
  int c = lane & 15, g = lane >> 4;

  __shared__ __align__(16) char smem[39952];
  ushort* rkb  = (ushort*)smem;
  float*  redp = (float*)smem;
  ushort* Ab1  = (ushort*)smem;
  ushort* Ab2  = (ushort*)(smem + 9216);
  float*  Af   = (float*)(smem + 21760);
  ushort* xT   = (ushort*)(smem + 18432);
  float*  gpow  = (float*)(smem + 39168);
  float*  betaS = (float*)(smem + 39432);
  float*  bd    = (float*)(smem + 39688);

  float lg = logf(1.f / (1.f + expf(-decay[h])));
  if (tid < 65) gpow[tid] = expf(lg * (float)tid);
  if (tid < 64) betaS[tid] = beta[(size_t)bh * T_LEN + n * 64 + tid];
  const int t0 = n * 64;
  const size_t bhbase = (size_t)bh * T_LEN;
  const us8 zero8 = {0, 0, 0, 0, 0, 0, 0, 0};

  #pragma unroll
  for (int u = 0; u < 5; ++u) {
    int idx = tid + u * 256;
    int row = idx >> 4, cb = idx & 15;
    us8 v = zero8;
    int t = t0 + row - 1;
    if (row <= 64 && t >= 0) v = *(const us8*)(rk + (bhbase + t) * 128 + cb * 8);
    *(us8*)&rkb[row * 136 + cb * 8] = v;
  }
  for (int idx = tid; idx < 64 * 68; idx += 256) Af[idx] = 0.f;
  __syncthreads();
  if (tid < 64) bd[tid] = betaS[tid] * gpow[tid + 1];

  const size_t abase = ((size_t)bh * 64 + n) * 4096;
  {
    const int TR[14] = {0,1,1,2,2,2,3,3,3,3,4,4,4,4};
    const int TC[14] = {0,0,1,0,1,2,0,1,2,3,0,1,2,3};
    #pragma unroll
    for (int ti = 0; ti < 14; ++ti) {
      if ((ti & 3) != w) continue;
      const int tr = TR[ti], tc = TC[ti];
      f32x4 acc = {0.f, 0.f, 0.f, 0.f};
      #pragma unroll
      for (int ks = 0; ks < 4; ++ks) {
        short8v a = *(const short8v*)&rkb[(tr * 16 + c) * 136 + ks * 32 + g * 8];
        short8v b = *(const short8v*)&rkb[(tc * 16 + c) * 136 + ks * 32 + g * 8];
        acc = __builtin_amdgcn_mfma_f32_16x16x32_bf16(a, b, acc, 0, 0, 0);
      }
      #pragma unroll
      for (int r = 0; r < 4; ++r) {
        int a_ = tr * 16 + g * 4 + r;
        int j = tc * 16 + c;
        float val = acc[r];
        if (a_ <= 63) Af[a_ * 68 + j] = (a_ > j) ? (-betaS[a_] * val * gpow[a_ - j]) : 0.f;
        if (a_ >= 1 && a_ <= 64) {
          if (j <= a_ - 1)      attn[abase + (size_t)(a_ - 1) * 64 + j] = f2bf(val * gpow[a_ - 1 - j]);
          else if (a_ <= 63)    attn[abase + (size_t)(a_ - 1) * 64 + j] = 0;
        }
      }
    }
  }
  {
    const int ZR[6] = {0,0,0,1,1,2};
    const int ZC[6] = {1,2,3,2,3,3};
    int rr = tid >> 4, cc2 = tid & 15;
    #pragma unroll
    for (int z = 0; z < 6; ++z) {
      int r_att = ZR[z] * 16 - 1 + rr;
      if (r_att >= 0) attn[abase + (size_t)r_att * 64 + ZC[z] * 16 + cc2] = 0;
    }
  }
  __syncthreads();

  {
    int k = tid & 63, sp = tid >> 6;
    for (int i = 1; i < 64; ++i) {
      float part = 0.f;
      #pragma unroll
      for (int jj = 0; jj < 16; ++jj) {
        int j = sp * 16 + jj;
        part += Af[i * 68 + j] * Af[j * 68 + k];
      }
      redp[sp * 64 + k] = part;
      __syncthreads();
      if (tid < 64) Af[i * 68 + tid] += redp[tid] + redp[64 + tid] + redp[128 + tid] + redp[192 + tid];
      __syncthreads();
    }
  }
  {
    int i = tid >> 2, j0 = (tid & 3) * 16;
    #pragma unroll
    for (int jj = 0; jj < 16; ++jj) {
      int j = j0 + jj;
      float av = Af[i * 68 + j] + ((i == j) ? 1.f : 0.f);
      Ab1[i * 72 + j] = f2bf(av * bd[j]);
      Ab2[i * 72 + j] = f2bf(av);
    }
  }
  __syncthreads();

  #pragma unroll
  for (int u = 0; u < 4; ++u) {
    int idx = tid + u * 256;
    int j = idx & 63, eb = idx >> 6;
    int t = t0 + j - 1;
    us8 v = zero8;
    if (t >= 0) v = *(const us8*)(rk + (bhbase + t) * 128 + eb * 8);
    #pragma unroll
    for (int s = 0; s < 8; ++s) xT[(eb * 8 + s) * 72 + j] = v[s];
  }
  __syncthreads();

  {
    f32x4 acc[8] = {};
    #pragma unroll
    for (int ks = 0; ks < 2; ++ks) {
      short8v a = *(const short8v*)&Ab1[(w * 16 + c) * 72 + ks * 32 + g * 8];
      #pragma unroll
      for (int nt = 0; nt < 8; ++nt) {
        short8v b = *(const short8v*)&xT[(nt * 16 + c) * 72 + ks * 32 + g * 8];
        acc[nt] = __builtin_amdgcn_mfma_f32_16x16x32_bf16(a, b, acc[nt], 0, 0, 0);
      }
    }
    #pragma unroll
    for (int nt = 0; nt < 8; ++nt)
      #pragma unroll
      for (int r = 0; r < 4; ++r) {
        int i = w * 16 + g * 4 + r, e = nt * 16 + c;
        wkcum[(bhbase + t0 + i) * 128 + e] = f2bf(acc[nt][r]);
      }
  }
  {
    const size_t kbase = ((size_t)bh * 64 + n) * 8192;
    #pragma unroll
    for (int u = 0; u < 4; ++u) {
      int idx = tid + u * 256;
      int e = idx >> 3, seg = idx & 7;
      us8 v = *(const us8*)&xT[e * 72 + seg * 8];
      us8 o;
      #pragma unroll
      for (int s = 0; s < 8; ++s) o[s] = f2bf(bf2f(v[s]) * gpow[63 - (seg * 8 + s)]);
      *(us8*)(wkdwT + kbase + (size_t)e * 64 + seg * 8) = o;
    }
  }
  __syncthreads();
  #pragma unroll
  for (int u = 0; u < 4; ++u) {
    int idx = tid + u * 256;
    int j = idx & 63, eb = idx >> 6;
    us8 v = *(const us8*)(vb + (bhbase + t0 + j) * 128 + eb * 8);
    #pragma unroll
    for (int s = 0; s < 8; ++s) xT[(eb * 8 + s) * 72 + j] = v[s];
  }
  __syncthreads();
  {
    f32x4 acc[8] = {};
    #pragma unroll
    for (int ks = 0; ks < 2; ++ks) {
      short8v a = *(const short8v*)&Ab2[(w * 16 + c) * 72 + ks * 32 + g * 8];
      #pragma unroll
      for (int nt = 0; nt < 8; ++nt) {
        short8v b = *(const short8v*)&xT[(nt * 16 + c) * 72 + ks * 32 + g * 8];
        acc[nt] = __builtin_amdgcn_mfma_f32_16x16x32_bf16(a, b, acc[nt], 0, 0, 0);
      }
    }
    #pragma unroll
    for (int nt = 0; nt < 8; ++nt)
      #pragma unroll
      for (int r = 0; r < 4; ++r) {
        int i = w * 16 + g * 4 + r, e = nt * 16 + c;
        vb[(bhbase + t0 + i) * 128 + e] = f2bf(acc[nt][r]);
      }
  }
}

// ---------------- K4: fused MFMA scan (verbatim R12/R14: 4 waves, 16-col, grid 256) ----------------
#define SCAN_STEP(W_, R_, T_, K_, V_, nW, nR, nT, nK, nV, n_) {                 \
  const int t0s = (n_) * 64;                                                    \
  { const int np = ((n_) < 63) ? (n_) + 1 : 63;                                 \
    const size_t rb = (bhbase + (size_t)(np * 64 + 16 * w + c)) * 128;          \
    _Pragma("unroll")                                                           \
    for (int ks = 0; ks < 4; ++ks) {                                            \
      nW[ks] = *(const short8v*)(wkcum + rb + ks * 32 + g * 8);                 \
      nR[ks] = *(const short8v*)(rk    + rb + ks * 32 + g * 8); }               \
    const size_t ab = ((size_t)bh * 64 + np) * 4096 + (size_t)(16 * w + c) * 64;\
    nT[0] = *(const short8v*)(attn + ab + g * 8);                               \
    nT[1] = *(const short8v*)(attn + ab + 32 + g * 8);                          \
    const size_t kb = ((size_t)bh * 64 + np) * 8192;                            \
    nK[0] = *(const short8v*)(wkdwT + kb + (size_t)(32 * w + c) * 64 + g * 8);  \
    nK[1] = *(const short8v*)(wkdwT + kb + (size_t)(32 * w + c) * 64 + 32 + g * 8); \
    nK[2] = *(const short8v*)(wkdwT + kb + (size_t)(32 * w + 16 + c) * 64 + g * 8); \
    nK[3] = *(const short8v*)(wkdwT + kb + (size_t)(32 * w + 16 + c) * 64 + 32 + g * 8); \
    _Pragma("unroll")                                                           \
    for (int r = 0; r < 4; ++r)                                                 \
      nV[r] = vb[(bhbase + (size_t)(np * 64 + 16 * w + 4 * g + r)) * 128 + q0 + c]; } \
  f32x4 accA = {}, accB = {};                                                   \
  _Pragma("unroll")                                                             \
  for (int ks = 0; ks < 4; ++ks) {                                              \
    short8v b0 = *(const short8v*)&ST[c * 136 + ks * 32 + g * 8];               \
    accA = __builtin_amdgcn_mfma_f32_16x16x32_bf16(W_[ks], b0, accA, 0, 0, 0);  \
    accB = __builtin_amdgcn_mfma_f32_16x16x32_bf16(R_[ks], b0, accB, 0, 0, 0); }\
  _Pragma("unroll")                                                             \
  for (int r = 0; r < 4; ++r) {                                                 \
    int i = 16 * w + 4 * g + r;                                                 \
    accB[r] *= gB[r];                                                           \
    vnL[c * 72 + i] = f2bf(bf2f(V_[r]) - accA[r]); }                            \
  asm volatile("s_waitcnt lgkmcnt(0)" ::: "memory");                            \
  __builtin_amdgcn_s_barrier();                                                 \
  short8v vf0 = *(const short8v*)&vnL[c * 72 + g * 8];                          \
  short8v vf1 = *(const short8v*)&vnL[c * 72 + 32 + g * 8];                     \
  accB = __builtin_amdgcn_mfma_f32_16x16x32_bf16(T_[0], vf0, accB, 0, 0, 0);    \
  accB = __builtin_amdgcn_mfma_f32_16x16x32_bf16(T_[1], vf1, accB, 0, 0, 0);    \
  _Pragma("unroll")                                                             \
  for (int r = 0; r < 4; ++r) {                                                 \
    int i = 16 * w + 4 * g + r;                                                 \
    og[((size_t)b_ * T_LEN + t0s + i) * 1024 + h * 128 + q0 + c] = f2bf(accB[r]); } \
  _Pragma("unroll")                                                             \
  for (int r = 0; r < 4; ++r) { accS0[r] *= ct; accS1[r] *= ct; }               \
  accS0 = __builtin_amdgcn_mfma_f32_16x16x32_bf16(K_[0], vf0, accS0, 0, 0, 0);  \
  accS0 = __builtin_amdgcn_mfma_f32_16x16x32_bf16(K_[1], vf1, accS0, 0, 0, 0);  \
  accS1 = __builtin_amdgcn_mfma_f32_16x16x32_bf16(K_[2], vf0, accS1, 0, 0, 0);  \
  accS1 = __builtin_amdgcn_mfma_f32_16x16x32_bf16(K_[3], vf1, accS1, 0, 0, 0);  \
  _Pragma("unroll")                                                             \
  for (int r = 0; r < 4; ++r) {                                                 \
    int p0r = 32 * w + 4 * g + r;                                               \
    ST[c * 136 + p0r]      = f2bf(accS0[r]);                                    \
    ST[c * 136 + p0r + 16] = f2bf(accS1[r]); }                                  \
  asm volatile("s_waitcnt lgkmcnt(0)" ::: "memory");                            \
  __builtin_amdgcn_s_barrier();                                                 \
}

__global__ __launch_bounds__(256) void k_scan_fused(
    const ushort* __restrict__ rk, const ushort* __restrict__ vb,
    const ushort* __restrict__ wkcum, const ushort* __restrict__ attn,
    const ushort* __restrict__ wkdwT, const float* __restrict__ decay,
    ushort* __restrict__ og)
{
  const int bh = blockIdx.x & 31;
  const int q0 = (blockIdx.x >> 5) * 16;
  const int b_ = bh >> 3, h = bh & 7;
  const int tid = threadIdx.x;
  const int lane = tid & 63, w = tid >> 6;
  const int c = lane & 15, g = lane >> 4;

  __shared__ ushort ST[16 * 136];
  __shared__ ushort vnL[16 * 72];
  __shared__ float gpow[65];

  float lg = logf(1.f / (1.f + expf(-decay[h])));
  if (tid < 65) gpow[tid] = expf(lg * (float)tid);
  for (int idx = tid; idx < 16 * 136; idx += 256) ST[idx] = 0;
  __syncthreads();
  const float ct = gpow[64];
  float gB[4];
  #pragma unroll
  for (int r = 0; r < 4; ++r) gB[r] = gpow[16 * w + 4 * g + r + 1];
  const size_t bhbase = (size_t)bh * T_LEN;

  f32x4 accS0 = {}, accS1 = {};
  short8v aW[4], aR[4], aT[2], aK[4];
  short8v bW[4], bR[4], bT[2], bK[4];
  ushort aV[4], bV[4];
  {
    const size_t rb = (bhbase + (size_t)(16 * w + c)) * 128;
    #pragma unroll
    for (int ks = 0; ks < 4; ++ks) {
      aW[ks] = *(const short8v*)(wkcum + rb + ks * 32 + g * 8);
      aR[ks] = *(const short8v*)(rk + rb + ks * 32 + g * 8);
    }
    const size_t ab = (size_t)bh * 64 * 4096 + (size_t)(16 * w + c) * 64;
    aT[0] = *(const short8v*)(attn + ab + g * 8);
    aT[1] = *(const short8v*)(attn + ab + 32 + g * 8);
    const size_t kb = (size_t)bh * 64 * 8192;
    aK[0] = *(const short8v*)(wkdwT + kb + (size_t)(32 * w + c) * 64 + g * 8);
    aK[1] = *(const short8v*)(wkdwT + kb + (size_t)(32 * w + c) * 64 + 32 + g * 8);
    aK[2] = *(const short8v*)(wkdwT + kb + (size_t)(32 * w + 16 + c) * 64 + g * 8);
    aK[3] = *(const short8v*)(wkdwT + kb + (size_t)(32 * w + 16 + c) * 64 + 32 + g * 8);
    #pragma unroll
    for (int r = 0; r < 4; ++r)
      aV[r] = vb[(bhbase + (size_t)(16 * w + 4 * g + r)) * 128 + q0 + c];
  }
  for (int n = 0; n < 64; n += 2) {
    SCAN_STEP(aW, aR, aT, aK, aV, bW, bR, bT, bK, bV, n);
    SCAN_STEP(bW, bR, bT, bK, bV, aW, aR, aT, aK, aV, n + 1);
  }
}

extern "C" void kernel_launch(void* const* d_in, const int* in_sizes, int n_in,
                              void* d_out, int out_size, void* d_ws, size_t ws_size,
                              hipStream_t stream) {
  const float* x   = (const float*)d_in[0];
  const float* Ww  = (const float*)d_in[1];
  const float* Wr  = (const float*)d_in[2];
  const float* Wb  = (const float*)d_in[3];
  const float* dec = (const float*)d_in[4];
  float* out = (float*)d_out;
  ushort* ws = (ushort*)d_ws;
  const size_t SZ = 16777216ull;
  ushort* rk    = ws;
  ushort* vb    = ws + SZ;
  ushort* wkcum = ws + 2 * SZ;
  ushort* og    = ws + 3 * SZ;
  ushort* attn  = ws + 4 * SZ;
  float*  beta  = (float*)(ws + 4 * SZ + 8388608ull);
  ushort* wkdwT = ws + 4 * SZ + 8388608ull + 262144ull;
  ushort* Wwb   = ws + 92536832ull;
  ushort* Wrb   = ws + 93585408ull;
  ushort* xb    = og;
  const size_t NEED = 189267968ull;
  if (ws_size < NEED) {
    hipMemcpyAsync(d_out, (const void*)x, (size_t)out_size * 4, hipMemcpyDeviceToDevice, stream);
    return;
  }

  k_wcvt<<<dim3(512), dim3(256), 0, stream>>>(Ww, Wr, Wwb, Wrb);
  k_prep<<<dim3(16384), dim3(128), 0, stream>>>(x, Wb, rk, beta, xb);
  k_gemm<0><<<dim3(8, 128), dim3(256), 0, stream>>>(xb, Wwb, beta, nullptr, (void*)vb);
  k_chunk<<<dim3(2048), dim3(256), 0, stream>>>(rk, vb, wkcum, attn, beta, dec, wkdwT);
  k_scan_fused<<<dim3(256), dim3(256), 0, stream>>>(rk, vb, wkcum, attn, wkdwT, dec, og);
  k_gemm<1><<<dim3(8, 128), dim3(256), 0, stream>>>(og, Wrb, nullptr, (const float*)x, (void*)out);
}

// Round 17
// 372.053 us; speedup vs baseline: 1.2552x; 1.0527x over previous
//
#include <hip/hip_runtime.h>
#include <hip/hip_bf16.h>
#include <math.h>

// HebbianBlock: B=4, T=4096, D=1024, H=8, d=128, C=64, N=64
// Round 17: exact revert to Round 14 (best verified: 372.2 us). R16's dbuf
// GEMM doubled LDS -> occupancy 4->2 blocks/CU and regressed (m132 lesson).
// Pipeline: k_wcvt | k_prep (rk,beta,xb) | k_gemm<0> (gload_lds staging) |
// k_chunk (overlaid 40KB LDS, serial-f32 UT, MFMA G/4a/4b, wkdwT export) |
// k_scan_fused (4-wave, 16-col, grid 256, full double-buffered prefetch) |
// k_gemm<1>.

#define T_LEN 4096
typedef unsigned short ushort;
typedef __attribute__((ext_vector_type(2))) unsigned short us2;
typedef __attribute__((ext_vector_type(4))) unsigned short us4;
typedef __attribute__((ext_vector_type(8))) unsigned short us8;
typedef __attribute__((ext_vector_type(8))) short short8v;
typedef __attribute__((ext_vector_type(4))) float f32x4;

__device__ __forceinline__ float bf2f(ushort u) {
  union { unsigned int u; float f; } c; c.u = ((unsigned int)u) << 16; return c.f;
}
__device__ __forceinline__ ushort f2bf(float x) {
  union { float f; unsigned int u; } c; c.f = x;
  unsigned int u = c.u + 0x7FFFu + ((c.u >> 16) & 1u);
  return (ushort)(u >> 16);
}
__device__ __forceinline__ void gload_lds16(const ushort* g, ushort* l) {
  __builtin_amdgcn_global_load_lds(
      (const __attribute__((address_space(1))) void*)g,
      (__attribute__((address_space(3))) void*)l, 16, 0, 0);
}

// ---------------- K0: W f32 -> bf16 ----------------
__global__ __launch_bounds__(256) void k_wcvt(
    const float* __restrict__ Ww, const float* __restrict__ Wr,
    ushort* __restrict__ Wwb, ushort* __restrict__ Wrb)
{
  size_t i = ((size_t)blockIdx.x * 256 + threadIdx.x) * 8;
  float4 p0 = *(const float4*)(Ww + i), p1 = *(const float4*)(Ww + i + 4);
  us8 o;
  o[0]=f2bf(p0.x); o[1]=f2bf(p0.y); o[2]=f2bf(p0.z); o[3]=f2bf(p0.w);
  o[4]=f2bf(p1.x); o[5]=f2bf(p1.y); o[6]=f2bf(p1.z); o[7]=f2bf(p1.w);
  *(us8*)(Wwb + i) = o;
  float4 q0 = *(const float4*)(Wr + i), q1 = *(const float4*)(Wr + i + 4);
  us8 o2;
  o2[0]=f2bf(q0.x); o2[1]=f2bf(q0.y); o2[2]=f2bf(q0.z); o2[3]=f2bf(q0.w);
  o2[4]=f2bf(q1.x); o2[5]=f2bf(q1.y); o2[6]=f2bf(q1.z); o2[7]=f2bf(q1.w);
  *(us8*)(Wrb + i) = o2;
}

// ---------------- K1: rk + beta + xb ----------------
__global__ __launch_bounds__(128) void k_prep(
    const float* __restrict__ x, const float* __restrict__ Wb,
    ushort* __restrict__ rk, float* __restrict__ beta, ushort* __restrict__ xb)
{
  int bt = blockIdx.x;
  int b = bt >> 12, t = bt & 4095;
  int tid = threadIdx.x;
  __shared__ float xs[1024];
  __shared__ float red[16];
  {
    const float4* x4 = (const float4*)(x + (size_t)bt * 1024);
    float4* xs4 = (float4*)xs;
    xs4[tid] = x4[tid];
    xs4[tid + 128] = x4[tid + 128];
  }
  __syncthreads();
  int h = tid >> 4;
  int e0 = h * 128 + (tid & 15) * 8;
  float ss = 0.f;
  #pragma unroll
  for (int s = 0; s < 8; ++s) { float v = xs[e0 + s]; ss += v * v; }
  #pragma unroll
  for (int m = 1; m < 16; m <<= 1) ss += __shfl_xor(ss, m, 64);
  float inv = 1.f / fmaxf(sqrtf(ss), 1e-12f);
  {
    int bh = b * 8 + h;
    us8 o;
    #pragma unroll
    for (int s = 0; s < 8; ++s) o[s] = f2bf(xs[e0 + s] * inv);
    *(us8*)(rk + ((size_t)bh * T_LEN + t) * 128 + (tid & 15) * 8) = o;
  }
  {
    us8 o;
    #pragma unroll
    for (int s = 0; s < 8; ++s) o[s] = f2bf(xs[tid * 8 + s]);
    *(us8*)(xb + (size_t)bt * 1024 + tid * 8) = o;
  }
  const float* xk = xs + tid * 8;
  #pragma unroll
  for (int h2 = 0; h2 < 8; ++h2) {
    const float* wb = Wb + (size_t)h2 * 1024 + tid * 8;
    float p = 0.f;
    #pragma unroll
    for (int s = 0; s < 8; ++s) p += xk[s] * wb[s];
    #pragma unroll
    for (int m = 1; m < 64; m <<= 1) p += __shfl_xor(p, m, 64);
    if ((tid & 63) == 0) red[(tid >> 6) * 8 + h2] = p;
  }
  __syncthreads();
  if (tid < 8) {
    float s = red[tid] + red[8 + tid];
    beta[((size_t)(b * 8 + tid)) * T_LEN + t] = 1.f / (1.f + expf(-s));
  }
}

// ---------------- K2/K5: bf16 MFMA GEMM, global_load_lds staging ----------------
template<int MODE>
__global__ __launch_bounds__(256) void k_gemm(
    const ushort* __restrict__ A, const ushort* __restrict__ Wb,
    const float* __restrict__ beta, const float* __restrict__ xadd,
    void* __restrict__ out_)
{
  __shared__ ushort As[128 * 32];
  __shared__ ushort Bs[128 * 32];
  const int n0 = blockIdx.x * 128;
  const int m0 = blockIdx.y * 128;
  const int tid = threadIdx.x;
  const int lane = tid & 63;
  const int wid = tid >> 6;
  const int wr = wid >> 1, wc = wid & 1;
  const int c = lane & 15, g = lane >> 4;
  const int lrow = lane >> 2;
  const int lseg = lane & 3;

  f32x4 acc[4][4] = {};

  for (int k0 = 0; k0 < 1024; k0 += 32) {
    #pragma unroll
    for (int u = 0; u < 2; ++u) {
      const int rbase = wid * 32 + u * 16;
      const int row = rbase + lrow;
      gload_lds16(A  + (size_t)(m0 + row) * 1024 + k0 + lseg * 8, &As[rbase * 32]);
      gload_lds16(Wb + (size_t)(n0 + row) * 1024 + k0 + lseg * 8, &Bs[rbase * 32]);
    }
    __syncthreads();
    short8v af[4], bf[4];
    #pragma unroll
    for (int mi = 0; mi < 4; ++mi)
      af[mi] = *(const short8v*)&As[(wr * 64 + mi * 16 + c) * 32 + g * 8];
    #pragma unroll
    for (int ni = 0; ni < 4; ++ni)
      bf[ni] = *(const short8v*)&Bs[(wc * 64 + ni * 16 + c) * 32 + g * 8];
    #pragma unroll
    for (int mi = 0; mi < 4; ++mi)
      #pragma unroll
      for (int ni = 0; ni < 4; ++ni)
        acc[mi][ni] = __builtin_amdgcn_mfma_f32_16x16x32_bf16(af[mi], bf[ni], acc[mi][ni], 0, 0, 0);
    __syncthreads();
  }

  if (MODE == 0) {
    ushort* vb = (ushort*)out_;
    const int hh = n0 >> 7;
    #pragma unroll
    for (int mi = 0; mi < 4; ++mi) {
      #pragma unroll
      for (int ni = 0; ni < 4; ++ni) {
        int jc = wc * 64 + ni * 16 + c;
        #pragma unroll
        for (int j = 0; j < 4; ++j) {
          int m = m0 + wr * 64 + mi * 16 + g * 4 + j;
          int b = m >> 12, t = m & 4095;
          size_t base = (size_t)(b * 8 + hh) * T_LEN + t;
          float bv = beta[base];
          vb[base * 128 + jc] = f2bf(acc[mi][ni][j] * bv);
        }
      }
    }
  } else {
    float* out = (float*)out_;
    #pragma unroll
    for (int mi = 0; mi < 4; ++mi) {
      #pragma unroll
      for (int ni = 0; ni < 4; ++ni) {
        int n = n0 + wc * 64 + ni * 16 + c;
        #pragma unroll
        for (int j = 0; j < 4; ++j) {
          int m = m0 + wr * 64 + mi * 16 + g * 4 + j;
          size_t idx = (size_t)m * 1024 + n;
          out[idx] = xadd[idx] + acc[mi][ni][j];
        }
      }
    }
  }
}

// ---------------- K3: chunk kernel (overlaid 40KB LDS, serial-f32 UT) ----------------
__global__ __launch_bounds__(256) void k_chunk(
    const ushort* __restrict__ rk, ushort* __restrict__ vb,
    ushort* __restrict__ wkcum, ushort* __restrict__ attn,
    const float* __restrict__ beta, const float* __restrict__ decay,
    ushort* __restrict__ wkdwT)
{
  int bh = blockIdx.x >> 6;
  int n = blockIdx.x & 63;
  int h = bh & 7;
  int tid = threadIdx.x;
  int lane = tid & 63, w = tid >> 6;
  int c = lane & 15, g = lane >> 4;

  __shared__ __align__(16) char smem[39952];
  ushort* rkb  = (ushort*)smem;
  float*  redp = (float*)smem;
  ushort* Ab1  = (ushort*)smem;
  ushort* Ab2  = (ushort*)(smem + 9216);
  float*  Af   = (float*)(smem + 21760);
  ushort* xT   = (ushort*)(smem + 18432);
  float*  gpow  = (float*)(smem + 39168);
  float*  betaS = (float*)(smem + 39432);
  float*  bd    = (float*)(smem + 39688);

  float lg = logf(1.f / (1.f + expf(-decay[h])));
  if (tid < 65) gpow[tid] = expf(lg * (float)tid);
  if (tid < 64) betaS[tid] = beta[(size_t)bh * T_LEN + n * 64 + tid];
  const int t0 = n * 64;
  const size_t bhbase = (size_t)bh * T_LEN;
  const us8 zero8 = {0, 0, 0, 0, 0, 0, 0, 0};

  #pragma unroll
  for (int u = 0; u < 5; ++u) {
    int idx = tid + u * 256;
    int row = idx >> 4, cb = idx & 15;
    us8 v = zero8;
    int t = t0 + row - 1;
    if (row <= 64 && t >= 0) v = *(const us8*)(rk + (bhbase + t) * 128 + cb * 8);
    *(us8*)&rkb[row * 136 + cb * 8] = v;
  }
  for (int idx = tid; idx < 64 * 68; idx += 256) Af[idx] = 0.f;
  __syncthreads();
  if (tid < 64) bd[tid] = betaS[tid] * gpow[tid + 1];

  const size_t abase = ((size_t)bh * 64 + n) * 4096;
  {
    const int TR[14] = {0,1,1,2,2,2,3,3,3,3,4,4,4,4};
    const int TC[14] = {0,0,1,0,1,2,0,1,2,3,0,1,2,3};
    #pragma unroll
    for (int ti = 0; ti < 14; ++ti) {
      if ((ti & 3) != w) continue;
      const int tr = TR[ti], tc = TC[ti];
      f32x4 acc = {0.f, 0.f, 0.f, 0.f};
      #pragma unroll
      for (int ks = 0; ks < 4; ++ks) {
        short8v a = *(const short8v*)&rkb[(tr * 16 + c) * 136 + ks * 32 + g * 8];
        short8v b = *(const short8v*)&rkb[(tc * 16 + c) * 136 + ks * 32 + g * 8];
        acc = __builtin_amdgcn_mfma_f32_16x16x32_bf16(a, b, acc, 0, 0, 0);
      }
      #pragma unroll
      for (int r = 0; r < 4; ++r) {
        int a_ = tr * 16 + g * 4 + r;
        int j = tc * 16 + c;
        float val = acc[r];
        if (a_ <= 63) Af[a_ * 68 + j] = (a_ > j) ? (-betaS[a_] * val * gpow[a_ - j]) : 0.f;
        if (a_ >= 1 && a_ <= 64) {
          if (j <= a_ - 1)      attn[abase + (size_t)(a_ - 1) * 64 + j] = f2bf(val * gpow[a_ - 1 - j]);
          else if (a_ <= 63)    attn[abase + (size_t)(a_ - 1) * 64 + j] = 0;
        }
      }
    }
  }
  {
    const int ZR[6] = {0,0,0,1,1,2};
    const int ZC[6] = {1,2,3,2,3,3};
    int rr = tid >> 4, cc2 = tid & 15;
    #pragma unroll
    for (int z = 0; z < 6; ++z) {
      int r_att = ZR[z] * 16 - 1 + rr;
      if (r_att >= 0) attn[abase + (size_t)r_att * 64 + ZC[z] * 16 + cc2] = 0;
    }
  }
  __syncthreads();

  {
    int k = tid & 63, sp = tid >> 6;
    for (int i = 1; i < 64; ++i) {
      float part = 0.f;
      #pragma unroll
      for (int jj = 0; jj < 16; ++jj) {
        int j = sp * 16 + jj;
        part += Af[i * 68 + j] * Af[j * 68 + k];
      }
      redp[sp * 64 + k] = part;
      __syncthreads();
      if (tid < 64) Af[i * 68 + tid] += redp[tid] + redp[64 + tid] + redp[128 + tid] + redp[192 + tid];
      __syncthreads();
    }
  }
  {
    int i = tid >> 2, j0 = (tid & 3) * 16;
    #pragma unroll
    for (int jj = 0; jj < 16; ++jj) {
      int j = j0 + jj;
      float av = Af[i * 68 + j] + ((i == j) ? 1.f : 0.f);
      Ab1[i * 72 + j] = f2bf(av * bd[j]);
      Ab2[i * 72 + j] = f2bf(av);
    }
  }
  __syncthreads();

  #pragma unroll
  for (int u = 0; u < 4; ++u) {
    int idx = tid + u * 256;
    int j = idx & 63, eb = idx >> 6;
    int t = t0 + j - 1;
    us8 v = zero8;
    if (t >= 0) v = *(const us8*)(rk + (bhbase + t) * 128 + eb * 8);
    #pragma unroll
    for (int s = 0; s < 8; ++s) xT[(eb * 8 + s) * 72 + j] = v[s];
  }
  __syncthreads();

  {
    f32x4 acc[8] = {};
    #pragma unroll
    for (int ks = 0; ks < 2; ++ks) {
      short8v a = *(const short8v*)&Ab1[(w * 16 + c) * 72 + ks * 32 + g * 8];
      #pragma unroll
      for (int nt = 0; nt < 8; ++nt) {
        short8v b = *(const short8v*)&xT[(nt * 16 + c) * 72 + ks * 32 + g * 8];
        acc[nt] = __builtin_amdgcn_mfma_f32_16x16x32_bf16(a, b, acc[nt], 0, 0, 0);
      }
    }
    #pragma unroll
    for (int nt = 0; nt < 8; ++nt)
      #pragma unroll
      for (int r = 0; r < 4; ++r) {
        int i = w * 16 + g * 4 + r, e = nt * 16 + c;
        wkcum[(bhbase + t0 + i) * 128 + e] = f2bf(acc[nt][r]);
      }
  }
  {
    const size_t kbase = ((size_t)bh * 64 + n) * 8192;
    #pragma unroll
    for (int u = 0; u < 4; ++u) {
      int idx = tid + u * 256;
      int e = idx >> 3, seg = idx & 7;
      us8 v = *(const us8*)&xT[e * 72 + seg * 8];
      us8 o;
      #pragma unroll
      for (int s = 0; s < 8; ++s) o[s] = f2bf(bf2f(v[s]) * gpow[63 - (seg * 8 + s)]);
      *(us8*)(wkdwT + kbase + (size_t)e * 64 + seg * 8) = o;
    }
  }
  __syncthreads();
  #pragma unroll
  for (int u = 0; u < 4; ++u) {
    int idx = tid + u * 256;
    int j = idx & 63, eb = idx >> 6;
    us8 v = *(const us8*)(vb + (bhbase + t0 + j) * 128 + eb * 8);
    #pragma unroll
    for (int s = 0; s < 8; ++s) xT[(eb * 8 + s) * 72 + j] = v[s];
  }
  __syncthreads();
  {
    f32x4 acc[8] = {};
    #pragma unroll
    for (int ks = 0; ks < 2; ++ks) {
      short8v a = *(const short8v*)&Ab2[(w * 16 + c) * 72 + ks * 32 + g * 8];
      #pragma unroll
      for (int nt = 0; nt < 8; ++nt) {
        short8v b = *(const short8v*)&xT[(nt * 16 + c) * 72 + ks * 32 + g * 8];
        acc[nt] = __builtin_amdgcn_mfma_f32_16x16x32_bf16(a, b, acc[nt], 0, 0, 0);
      }
    }
    #pragma unroll
    for (int nt = 0; nt < 8; ++nt)
      #pragma unroll
      for (int r = 0; r < 4; ++r) {
        int i = w * 16 + g * 4 + r, e = nt * 16 + c;
        vb[(bhbase + t0 + i) * 128 + e] = f2bf(acc[nt][r]);
      }
  }
}

// ---------------- K4: fused MFMA scan (4 waves, 16-col, grid 256) ----------------
#define SCAN_STEP(W_, R_, T_, K_, V_, nW, nR, nT, nK, nV, n_) {                 \
  const int t0s = (n_) * 64;                                                    \
  { const int np = ((n_) < 63) ? (n_) + 1 : 63;                                 \
    const size_t rb = (bhbase + (size_t)(np * 64 + 16 * w + c)) * 128;          \
    _Pragma("unroll")                                                           \
    for (int ks = 0; ks < 4; ++ks) {                                            \
      nW[ks] = *(const short8v*)(wkcum + rb + ks * 32 + g * 8);                 \
      nR[ks] = *(const short8v*)(rk    + rb + ks * 32 + g * 8); }               \
    const size_t ab = ((size_t)bh * 64 + np) * 4096 + (size_t)(16 * w + c) * 64;\
    nT[0] = *(const short8v*)(attn + ab + g * 8);                               \
    nT[1] = *(const short8v*)(attn + ab + 32 + g * 8);                          \
    const size_t kb = ((size_t)bh * 64 + np) * 8192;                            \
    nK[0] = *(const short8v*)(wkdwT + kb + (size_t)(32 * w + c) * 64 + g * 8);  \
    nK[1] = *(const short8v*)(wkdwT + kb + (size_t)(32 * w + c) * 64 + 32 + g * 8); \
    nK[2] = *(const short8v*)(wkdwT + kb + (size_t)(32 * w + 16 + c) * 64 + g * 8); \
    nK[3] = *(const short8v*)(wkdwT + kb + (size_t)(32 * w + 16 + c) * 64 + 32 + g * 8); \
    _Pragma("unroll")                                                           \
    for (int r = 0; r < 4; ++r)                                                 \
      nV[r] = vb[(bhbase + (size_t)(np * 64 + 16 * w + 4 * g + r)) * 128 + q0 + c]; } \
  f32x4 accA = {}, accB = {};                                                   \
  _Pragma("unroll")                                                             \
  for (int ks = 0; ks < 4; ++ks) {                                              \
    short8v b0 = *(const short8v*)&ST[c * 136 + ks * 32 + g * 8];               \
    accA = __builtin_amdgcn_mfma_f32_16x16x32_bf16(W_[ks], b0, accA, 0, 0, 0);  \
    accB = __builtin_amdgcn_mfma_f32_16x16x32_bf16(R_[ks], b0, accB, 0, 0, 0); }\
  _Pragma("unroll")                                                             \
  for (int r = 0; r < 4; ++r) {                                                 \
    int i = 16 * w + 4 * g + r;                                                 \
    accB[r] *= gB[r];                                                           \
    vnL[c * 72 + i] = f2bf(bf2f(V_[r]) - accA[r]); }                            \
  asm volatile("s_waitcnt lgkmcnt(0)" ::: "memory");                            \
  __builtin_amdgcn_s_barrier();                                                 \
  short8v vf0 = *(const short8v*)&vnL[c * 72 + g * 8];                          \
  short8v vf1 = *(const short8v*)&vnL[c * 72 + 32 + g * 8];                     \
  accB = __builtin_amdgcn_mfma_f32_16x16x32_bf16(T_[0], vf0, accB, 0, 0, 0);    \
  accB = __builtin_amdgcn_mfma_f32_16x16x32_bf16(T_[1], vf1, accB, 0, 0, 0);    \
  _Pragma("unroll")                                                             \
  for (int r = 0; r < 4; ++r) {                                                 \
    int i = 16 * w + 4 * g + r;                                                 \
    og[((size_t)b_ * T_LEN + t0s + i) * 1024 + h * 128 + q0 + c] = f2bf(accB[r]); } \
  _Pragma("unroll")                                                             \
  for (int r = 0; r < 4; ++r) { accS0[r] *= ct; accS1[r] *= ct; }               \
  accS0 = __builtin_amdgcn_mfma_f32_16x16x32_bf16(K_[0], vf0, accS0, 0, 0, 0);  \
  accS0 = __builtin_amdgcn_mfma_f32_16x16x32_bf16(K_[1], vf1, accS0, 0, 0, 0);  \
  accS1 = __builtin_amdgcn_mfma_f32_16x16x32_bf16(K_[2], vf0, accS1, 0, 0, 0);  \
  accS1 = __builtin_amdgcn_mfma_f32_16x16x32_bf16(K_[3], vf1, accS1, 0, 0, 0);  \
  _Pragma("unroll")                                                             \
  for (int r = 0; r < 4; ++r) {                                                 \
    int p0r = 32 * w + 4 * g + r;                                               \
    ST[c * 136 + p0r]      = f2bf(accS0[r]);                                    \
    ST[c * 136 + p0r + 16] = f2bf(accS1[r]); }                                  \
  asm volatile("s_waitcnt lgkmcnt(0)" ::: "memory");                            \
  __builtin_amdgcn_s_barrier();                                                 \
}

__global__ __launch_bounds__(256) void k_scan_fused(
    const ushort* __restrict__ rk, const ushort* __restrict__ vb,
    const ushort* __restrict__ wkcum, const ushort* __restrict__ attn,
    const ushort* __restrict__ wkdwT, const float* __restrict__ decay,
    ushort* __restrict__ og)
{
  const int bh = blockIdx.x & 31;
  const int q0 = (blockIdx.x >> 5) * 16;
  const int b_ = bh >> 3, h = bh & 7;
  const int tid = threadIdx.x;
  const int lane = tid & 63, w = tid >> 6;
  const int c = lane & 15, g = lane >> 4;

  __shared__ ushort ST[16 * 136];
  __shared__ ushort vnL[16 * 72];
  __shared__ float gpow[65];

  float lg = logf(1.f / (1.f + expf(-decay[h])));
  if (tid < 65) gpow[tid] = expf(lg * (float)tid);
  for (int idx = tid; idx < 16 * 136; idx += 256) ST[idx] = 0;
  __syncthreads();
  const float ct = gpow[64];
  float gB[4];
  #pragma unroll
  for (int r = 0; r < 4; ++r) gB[r] = gpow[16 * w + 4 * g + r + 1];
  const size_t bhbase = (size_t)bh * T_LEN;

  f32x4 accS0 = {}, accS1 = {};
  short8v aW[4], aR[4], aT[2], aK[4];
  short8v bW[4], bR[4], bT[2], bK[4];
  ushort aV[4], bV[4];
  {
    const size_t rb = (bhbase + (size_t)(16 * w + c)) * 128;
    #pragma unroll
    for (int ks = 0; ks < 4; ++ks) {
      aW[ks] = *(const short8v*)(wkcum + rb + ks * 32 + g * 8);
      aR[ks] = *(const short8v*)(rk + rb + ks * 32 + g * 8);
    }
    const size_t ab = (size_t)bh * 64 * 4096 + (size_t)(16 * w + c) * 64;
    aT[0] = *(const short8v*)(attn + ab + g * 8);
    aT[1] = *(const short8v*)(attn + ab + 32 + g * 8);
    const size_t kb = (size_t)bh * 64 * 8192;
    aK[0] = *(const short8v*)(wkdwT + kb + (size_t)(32 * w + c) * 64 + g * 8);
    aK[1] = *(const short8v*)(wkdwT + kb + (size_t)(32 * w + c) * 64 + 32 + g * 8);
    aK[2] = *(const short8v*)(wkdwT + kb + (size_t)(32 * w + 16 + c) * 64 + g * 8);
    aK[3] = *(const short8v*)(wkdwT + kb + (size_t)(32 * w + 16 + c) * 64 + 32 + g * 8);
    #pragma unroll
    for (int r = 0; r < 4; ++r)
      aV[r] = vb[(bhbase + (size_t)(16 * w + 4 * g + r)) * 128 + q0 + c];
  }
  for (int n = 0; n < 64; n += 2) {
    SCAN_STEP(aW, aR, aT, aK, aV, bW, bR, bT, bK, bV, n);
    SCAN_STEP(bW, bR, bT, bK, bV, aW, aR, aT, aK, aV, n + 1);
  }
}

extern "C" void kernel_launch(void* const* d_in, const int* in_sizes, int n_in,
                              void* d_out, int out_size, void* d_ws, size_t ws_size,
                              hipStream_t stream) {
  const float* x   = (const float*)d_in[0];
  const float* Ww  = (const float*)d_in[1];
  const float* Wr  = (const float*)d_in[2];
  const float* Wb  = (const float*)d_in[3];
  const float* dec = (const float*)d_in[4];
  float* out = (float*)d_out;
  ushort* ws = (ushort*)d_ws;
  const size_t SZ = 16777216ull;
  ushort* rk    = ws;
  ushort* vb    = ws + SZ;
  ushort* wkcum = ws + 2 * SZ;
  ushort* og    = ws + 3 * SZ;
  ushort* attn  = ws + 4 * SZ;
  float*  beta  = (float*)(ws + 4 * SZ + 8388608ull);
  ushort* wkdwT = ws + 4 * SZ + 8388608ull + 262144ull;
  ushort* Wwb   = ws + 92536832ull;
  ushort* Wrb   = ws + 93585408ull;
  ushort* xb    = og;
  const size_t NEED = 189267968ull;
  if (ws_size < NEED) {
    hipMemcpyAsync(d_out, (const void*)x, (size_t)out_size * 4, hipMemcpyDeviceToDevice, stream);
    return;
  }

  k_wcvt<<<dim3(512), dim3(256), 0, stream>>>(Ww, Wr, Wwb, Wrb);
  k_prep<<<dim3(16384), dim3(128), 0, stream>>>(x, Wb, rk, beta, xb);
  k_gemm<0><<<dim3(8, 128), dim3(256), 0, stream>>>(xb, Wwb, beta, nullptr, (void*)vb);
  k_chunk<<<dim3(2048), dim3(256), 0, stream>>>(rk, vb, wkcum, attn, beta, dec, wkdwT);
  k_scan_fused<<<dim3(256), dim3(256), 0, stream>>>(rk, vb, wkcum, attn, wkdwT, dec, og);
  k_gemm<1><<<dim3(8, 128), dim3(256), 0, stream>>>(og, Wrb, nullptr, (const float*)x, (void*)out);
}